// Round 11
// baseline (154.384 us; speedup 1.0000x reference)
//
#include <hip/hip_runtime.h>
#include <math.h>

// Problem constants
#define NTOK 16384
#define DDIM 4096
#define NEXP 64
#define KTOP 4

// Fused config: block = 32 tokens x all 64 experts x FULL K.
#define TPB  32                // tokens per block
#define NBLK (NTOK / TPB)      // 512 blocks -> 2 resident per CU
#define BK   128               // floats of k per stage
#define NSTG (DDIM / BK)       // 32 stages

typedef __attribute__((ext_vector_type(8))) short short8;
typedef __attribute__((ext_vector_type(4))) float f32x4;

// ws layout: Whi [NEXP][DDIM] ushort (512 KB) ; Wlo same (512 KB)

__device__ __forceinline__ unsigned short f2bf_rtn(float x) {
    unsigned int b = __float_as_uint(x);
    return (unsigned short)((b + 0x7FFFu + ((b >> 16) & 1u)) >> 16);
}
__device__ __forceinline__ float bf2f(unsigned short h) {
    return __uint_as_float(((unsigned int)h) << 16);
}
__device__ __forceinline__ short8 mk8(unsigned int a, unsigned int b,
                                      unsigned int c, unsigned int d) {
    union { unsigned int u[4]; short8 s; } p;
    p.u[0] = a; p.u[1] = b; p.u[2] = c; p.u[3] = d;
    return p.s;
}
__device__ __forceinline__ void gl2lds16(const void* g, void* l) {
    __builtin_amdgcn_global_load_lds(
        (const __attribute__((address_space(1))) unsigned int*)g,
        (__attribute__((address_space(3))) unsigned int*)l, 16, 0, 0);
}

// ---------------- Kernel 1: split W into bf16 hi/lo, zero counts -------------
__global__ __launch_bounds__(256) void prep_kernel(
    const float* __restrict__ W, unsigned short* __restrict__ Whi,
    unsigned short* __restrict__ Wlo, float* __restrict__ counts)
{
    int idx = blockIdx.x * 256 + threadIdx.x;   // 0 .. 64*4096
    float x = W[idx];
    unsigned short h = f2bf_rtn(x);
    float lo = x - bf2f(h);
    Whi[idx] = h;
    Wlo[idx] = f2bf_rtn(lo);
    if (blockIdx.x == 0 && threadIdx.x < NEXP) counts[threadIdx.x] = 0.0f;
}

// ---------------- Kernel 2: fused GEMM (bf16x3 MFMA) + routing ---------------
// 512 blocks x 512 threads (8 waves: 2m x 4n, wave tile 16 tok x 16 exp),
// LDS ~41 KB -> 2 BLOCKS RESIDENT PER CU (they cover each other's per-stage
// vmcnt drain, the R8-proven mechanism). X: gload_lds dbuf, source-swizzled.
// W: global->reg straight from L2 (2 MB resident). Routing fused in epilogue.
__global__ __launch_bounds__(512, 4) void gate_kernel(
    const float* __restrict__ X, const unsigned short* __restrict__ Whi,
    const unsigned short* __restrict__ Wlo, float* __restrict__ outW,
    float* __restrict__ outI, float* __restrict__ counts)
{
    __shared__ float sX[2][TPB * BK];   // 2 x 16 KB
    __shared__ float lgt[TPB][66];      // 8.4 KB logits
    __shared__ int   hist[NEXP];

    const int tid  = threadIdx.x;
    const int lane = tid & 63;
    const int w    = tid >> 6;                 // wave 0..7
    const int wm   = w >> 2;                   // token half   0..1
    const int wn   = w & 3;                    // expert quarter 0..3
    const int tok0 = blockIdx.x * TPB;

    if (tid < NEXP) hist[tid] = 0;

    // ---- X staging: wave w instr i covers LDS floats [w*512+i*256, +256) ----
    // = rows {w*4+i*2, +1}; lane -> row r = w*4+i*2+(lane>>5), phys chunk
    // p = lane&31 (16-B units). Source chunk = p ^ (r&15) (involution,
    // applied source-side; LDS dest stays linear per rule #21).
    const float* xsrc[2];
    int xdstf[2];
    #pragma unroll
    for (int i = 0; i < 2; ++i) {
        const int r = w * 4 + i * 2 + (lane >> 5);
        const int p = lane & 31;
        xsrc[i]  = X + (size_t)(tok0 + r) * DDIM + ((p ^ (r & 15)) * 4);
        xdstf[i] = w * 512 + i * 256;          // wave-uniform
    }

    // ---- prologue: stage 0 into buffer 0 ----
    gl2lds16(xsrc[0], &sX[0][xdstf[0]]);
    gl2lds16(xsrc[1], &sX[0][xdstf[1]]);
    __syncthreads();

    // ---- fragment geometry ----
    const int fr = lane & 15;                  // token row / expert col in frag
    const int fg = lane >> 4;                  // k subgroup 0..3
    const int rowA = (wm * 16 + fr) * BK;      // LDS float base of A row
    const unsigned short* wh = Whi + (size_t)(wn * 16 + fr) * DDIM + fg * 8;
    const unsigned short* wl = Wlo + (size_t)(wn * 16 + fr) * DDIM + fg * 8;

    f32x4 acc = (f32x4){0.f, 0.f, 0.f, 0.f};

    for (int st = 0; st < NSTG; ++st) {
        const float* cx = sX[st & 1];

        // ---- issue next stage's X loads (land during this stage's compute) --
        if (st + 1 < NSTG) {
            const int nb = (st + 1) & 1;
            const int ko = (st + 1) * BK;
            gl2lds16(xsrc[0] + ko, &sX[nb][xdstf[0]]);
            gl2lds16(xsrc[1] + ko, &sX[nb][xdstf[1]]);
        }

        // ---- 4 k-steps of 32: W from L2, A from LDS, convert, 3 MFMAs ------
        #pragma unroll
        for (int ks = 0; ks < 4; ++ks) {
            const int ko = st * BK + ks * 32;
            const short8 bh = *(const short8*)(wh + ko);
            const short8 bl = *(const short8*)(wl + ko);

            const int c0 = ks * 8 + fg * 2;    // logical 16-B chunk in row
            const float4 qa = *(const float4*)&cx[rowA + ((c0    ) ^ fr) * 4];
            const float4 qb = *(const float4*)&cx[rowA + ((c0 + 1) ^ fr) * 4];

            // RTZ split fp32 -> bf16 hi/lo
            const unsigned int u0 = __float_as_uint(qa.x), u1 = __float_as_uint(qa.y);
            const unsigned int u2 = __float_as_uint(qa.z), u3 = __float_as_uint(qa.w);
            const unsigned int u4 = __float_as_uint(qb.x), u5 = __float_as_uint(qb.y);
            const unsigned int u6 = __float_as_uint(qb.z), u7 = __float_as_uint(qb.w);
            const unsigned int hi0 = (u0 >> 16) | (u1 & 0xFFFF0000u);
            const unsigned int hi1 = (u2 >> 16) | (u3 & 0xFFFF0000u);
            const unsigned int hi2 = (u4 >> 16) | (u5 & 0xFFFF0000u);
            const unsigned int hi3 = (u6 >> 16) | (u7 & 0xFFFF0000u);
            const float l0 = qa.x - __uint_as_float(u0 & 0xFFFF0000u);
            const float l1 = qa.y - __uint_as_float(u1 & 0xFFFF0000u);
            const float l2 = qa.z - __uint_as_float(u2 & 0xFFFF0000u);
            const float l3 = qa.w - __uint_as_float(u3 & 0xFFFF0000u);
            const float l4 = qb.x - __uint_as_float(u4 & 0xFFFF0000u);
            const float l5 = qb.y - __uint_as_float(u5 & 0xFFFF0000u);
            const float l6 = qb.z - __uint_as_float(u6 & 0xFFFF0000u);
            const float l7 = qb.w - __uint_as_float(u7 & 0xFFFF0000u);
            const unsigned int lo0 = (__float_as_uint(l0) >> 16) | (__float_as_uint(l1) & 0xFFFF0000u);
            const unsigned int lo1 = (__float_as_uint(l2) >> 16) | (__float_as_uint(l3) & 0xFFFF0000u);
            const unsigned int lo2 = (__float_as_uint(l4) >> 16) | (__float_as_uint(l5) & 0xFFFF0000u);
            const unsigned int lo3 = (__float_as_uint(l6) >> 16) | (__float_as_uint(l7) & 0xFFFF0000u);
            const short8 ahi = mk8(hi0, hi1, hi2, hi3);
            const short8 alo = mk8(lo0, lo1, lo2, lo3);

            acc = __builtin_amdgcn_mfma_f32_16x16x32_bf16(ahi, bh, acc, 0, 0, 0);
            acc = __builtin_amdgcn_mfma_f32_16x16x32_bf16(ahi, bl, acc, 0, 0, 0);
            acc = __builtin_amdgcn_mfma_f32_16x16x32_bf16(alo, bh, acc, 0, 0, 0);
        }

        __syncthreads();   // drain covered by the co-resident block
    }

    // ---- epilogue: logits to LDS ----
    // C/D: col = fr (expert), row = fg*4 + r (token)
    #pragma unroll
    for (int r = 0; r < 4; ++r)
        lgt[wm * 16 + fg * 4 + r][wn * 16 + fr] = acc[r];
    __syncthreads();

    // ---- routing: wave w handles tokens tok0 + w*4 .. +3 ----
    for (int t = 0; t < 4; ++t) {
        const int nl = w * 4 + t;
        const int n  = tok0 + nl;
        const float L = lgt[nl][lane];

        // softmax over 64 experts (wave = expert axis)
        float m = L;
        #pragma unroll
        for (int off = 32; off > 0; off >>= 1) m = fmaxf(m, __shfl_xor(m, off));
        float p = expf(L - m);
        float ssum = p;
        #pragma unroll
        for (int off = 32; off > 0; off >>= 1) ssum += __shfl_xor(ssum, off);
        const float score = p / ssum;

        // group max within each 8-lane group
        float gm = score;
        gm = fmaxf(gm, __shfl_xor(gm, 1));
        gm = fmaxf(gm, __shfl_xor(gm, 2));
        gm = fmaxf(gm, __shfl_xor(gm, 4));

        // top-4 groups (ties -> lower index)
        float ga[8];
        #pragma unroll
        for (int g = 0; g < 8; ++g) ga[g] = __shfl(gm, g * 8);
        unsigned selmask = 0u;
        #pragma unroll
        for (int r = 0; r < 4; ++r) {
            float best = -INFINITY; int bg = 0;
            #pragma unroll
            for (int g = 0; g < 8; ++g) {
                bool taken  = (selmask >> g) & 1u;
                bool better = (!taken) && (ga[g] > best);
                bg   = better ? g : bg;
                best = better ? ga[g] : best;
            }
            selmask |= (1u << bg);
        }

        // mask non-selected groups, wave-wide top-4 (ties -> lower idx)
        float ms = ((selmask >> (lane >> 3)) & 1u) ? score : -INFINITY;
        float wk[4]; int wi[4];
        #pragma unroll
        for (int r = 0; r < 4; ++r) {
            float v = ms; int ix = lane;
            #pragma unroll
            for (int off = 32; off > 0; off >>= 1) {
                float vo = __shfl_xor(v, off);
                int   io = __shfl_xor(ix, off);
                if (vo > v || (vo == v && io < ix)) { v = vo; ix = io; }
            }
            wk[r] = v; wi[r] = ix;
            if (lane == ix) ms = -INFINITY;
        }

        if (lane == 0) {
            *(float4*)&outW[(size_t)n * 4] = make_float4(wk[0], wk[1], wk[2], wk[3]);
            *(float4*)&outI[(size_t)n * 4] =
                make_float4((float)wi[0], (float)wi[1], (float)wi[2], (float)wi[3]);
            atomicAdd(&hist[wi[0]], 1);
            atomicAdd(&hist[wi[1]], 1);
            atomicAdd(&hist[wi[2]], 1);
            atomicAdd(&hist[wi[3]], 1);
        }
    }

    __syncthreads();
    if (tid < NEXP) atomicAdd(&counts[tid], (float)hist[tid]);
}

extern "C" void kernel_launch(void* const* d_in, const int* in_sizes, int n_in,
                              void* d_out, int out_size, void* d_ws, size_t ws_size,
                              hipStream_t stream) {
    const float* X = (const float*)d_in[0];
    const float* W = (const float*)d_in[1];

    float* outW   = (float*)d_out;                    // [N,4] weights
    float* outI   = outW + (size_t)NTOK * KTOP;       // [N,4] indices (as float)
    float* counts = outW + (size_t)2 * NTOK * KTOP;   // [64]  counts  (as float)

    unsigned short* Whi = (unsigned short*)d_ws;               // 512 KB
    unsigned short* Wlo = Whi + (size_t)NEXP * DDIM;           // 512 KB

    prep_kernel<<<(NEXP * DDIM) / 256, 256, 0, stream>>>(W, Whi, Wlo, counts);
    gate_kernel<<<NBLK, 512, 0, stream>>>(X, Whi, Wlo, outW, outI, counts);
}

// Round 12
// 115.112 us; speedup vs baseline: 1.3412x; 1.3412x over previous
//
#include <hip/hip_runtime.h>
#include <math.h>

// Problem constants
#define NTOK 16384
#define DDIM 4096
#define NEXP 64
#define KTOP 4

// GEMM config
#define SPLITK 16
#define KPER (DDIM / SPLITK)   // 256 k per split
#define BK 32                  // k per stage (one 16x16x32 MFMA k-step)
#define NSTG (KPER / BK)       // 8 stages
#define WROWS 16               // tokens per wave
#define NWAVE 4                // waves per block (256 threads)
#define TPB (WROWS * NWAVE)    // 64 tokens per block
#define NBLK ((NTOK / TPB) * SPLITK)  // 4096 blocks

typedef __attribute__((ext_vector_type(8))) short short8;
typedef __attribute__((ext_vector_type(4))) float f32x4;

// ws layout: part [NTOK][SPLITK][NEXP] f32 = 64 MB ; Whi 512 KB ; Wlo 512 KB

__device__ __forceinline__ unsigned short f2bf_rtn(float x) {
    unsigned int b = __float_as_uint(x);
    return (unsigned short)((b + 0x7FFFu + ((b >> 16) & 1u)) >> 16);
}
__device__ __forceinline__ float bf2f(unsigned short h) {
    return __uint_as_float(((unsigned int)h) << 16);
}
__device__ __forceinline__ short8 mk8(unsigned int a, unsigned int b,
                                      unsigned int c, unsigned int d) {
    union { unsigned int u[4]; short8 s; } p;
    p.u[0] = a; p.u[1] = b; p.u[2] = c; p.u[3] = d;
    return p.s;
}
__device__ __forceinline__ void gl2lds16(const void* g, void* l) {
    __builtin_amdgcn_global_load_lds(
        (const __attribute__((address_space(1))) unsigned int*)g,
        (__attribute__((address_space(3))) unsigned int*)l, 16, 0, 0);
}

// ---------------- Kernel 1: split W into bf16 hi/lo, zero counts -------------
__global__ __launch_bounds__(256) void prep_kernel(
    const float* __restrict__ W, unsigned short* __restrict__ Whi,
    unsigned short* __restrict__ Wlo, float* __restrict__ counts)
{
    int idx = blockIdx.x * 256 + threadIdx.x;   // 0 .. 64*4096
    float x = W[idx];
    unsigned short h = f2bf_rtn(x);
    float lo = x - bf2f(h);
    Whi[idx] = h;
    Wlo[idx] = f2bf_rtn(lo);
    if (blockIdx.x == 0 && threadIdx.x < NEXP) counts[threadIdx.x] = 0.0f;
}

// ---------------- Kernel 2: bf16x3 MFMA GEMM, counted-vmcnt pipeline ---------
// 4096 blocks x 256 threads (4 waves), LDS 80 KB -> 2 blocks/CU.
// W slice (hi+lo, 64 KB) staged to LDS ONCE behind a single prologue barrier.
// X staged per-WAVE-PRIVATE LDS dbuf via global_load_lds; the K-loop has NO
// barriers: each wave orders its own DMA with counted `s_waitcnt vmcnt(2)`
// (never drains to 0 until the last stage) + sched_barrier(0)  [T3/T4].
__global__ __launch_bounds__(256, 2) void gemm_kernel(
    const float* __restrict__ X, const unsigned short* __restrict__ Whi,
    const unsigned short* __restrict__ Wlo, float* __restrict__ part)
{
    __shared__ unsigned short sH[NEXP * KPER];       // 32 KB
    __shared__ unsigned short sL[NEXP * KPER];       // 32 KB
    __shared__ float sXa[NWAVE][2][WROWS * BK];      // 16 KB (wave-private dbuf)

    const int tid  = threadIdx.x;
    const int lane = tid & 63;
    const int w    = tid >> 6;                 // wave 0..3
    const int tb   = blockIdx.x >> 4;          // token block 0..255
    const int s    = blockIdx.x & 15;          // k-split    0..15
    const int kbase = s * KPER;
    const int wtok  = tb * TPB + w * WROWS;    // this wave's first token row

    // ---- stage W slice hi+lo (16 gload_lds/thread), XOR-swizzled source ----
    // piece g (16 B): e = g>>5, p_lds = g&31; source piece = p_lds ^ (e&7)
    #pragma unroll
    for (int i = 0; i < 8; ++i) {
        const int g  = i * 256 + tid;
        const int e  = g >> 5;
        const int p  = g & 31;
        const int gb = (i * 256 + (tid >> 6) * 64) * 8;   // uniform base (shorts)
        const size_t src = (size_t)e * DDIM + kbase + ((p ^ (e & 7)) << 3);
        gl2lds16(Whi + src, &sH[gb]);
        gl2lds16(Wlo + src, &sL[gb]);
    }

    // ---- X staging geometry (wave-private): stage = 16 rows x 128 B = 2 instr
    // instr j: lane l -> row j*8+(l>>3), LDS piece l&7; source piece ^= row&7
    const int xrow = (lane >> 3);              // 0..7 within instr
    const int xp   = lane & 7;
    const float* xsrc0 = X + (size_t)(wtok + xrow) * DDIM + kbase
                       + ((xp ^ (xrow & 7)) << 2);
    const float* xsrc1 = X + (size_t)(wtok + 8 + xrow) * DDIM + kbase
                       + ((xp ^ ((xrow + 8) & 7)) << 2);   // rows 8..15, key = row&7 = xrow
    float* const xb0 = &sXa[w][0][0];
    float* const xb1 = &sXa[w][1][0];

#define ISSUE_X(buf, st)                                                    \
    {                                                                       \
        gl2lds16(xsrc0 + (st) * BK, (buf));                                 \
        gl2lds16(xsrc1 + (st) * BK, (buf) + 256);                           \
    }

    // prologue: stage 0 -> buf0, stage 1 -> buf1; barrier publishes W
    ISSUE_X(xb0, 0)
    ISSUE_X(xb1, 1)
    __syncthreads();   // drains vmcnt once; W + X stages 0,1 all ready

    // ---- fragment geometry ----
    const int fr = lane & 15;                  // token row / expert col in frag
    const int fg = lane >> 4;                  // k subgroup 0..3
    const int xkey = fr & 7;

    f32x4 acc[4];
    #pragma unroll
    for (int ng = 0; ng < 4; ++ng) acc[ng] = (f32x4){0.f, 0.f, 0.f, 0.f};

    #pragma unroll
    for (int st = 0; st < NSTG; ++st) {
        // counted wait: stage st's 2 DMAs done; stage st+1's 2 stay in flight
        if (st < NSTG - 1) {
            asm volatile("s_waitcnt vmcnt(2)" ::: "memory");
        } else {
            asm volatile("s_waitcnt vmcnt(0)" ::: "memory");
        }
        __builtin_amdgcn_sched_barrier(0);

        const float* cx = (st & 1) ? xb1 : xb0;

        // ---- A fragment: row fr, pieces {fg*2, fg*2+1} ^ key ----
        const float4 qa = *(const float4*)&cx[fr * BK + (((fg * 2    ) ^ xkey) << 2)];
        const float4 qb = *(const float4*)&cx[fr * BK + (((fg * 2 + 1) ^ xkey) << 2)];

        // ---- RTZ split fp32 -> bf16 hi/lo ----
        const unsigned int u0 = __float_as_uint(qa.x), u1 = __float_as_uint(qa.y);
        const unsigned int u2 = __float_as_uint(qa.z), u3 = __float_as_uint(qa.w);
        const unsigned int u4 = __float_as_uint(qb.x), u5 = __float_as_uint(qb.y);
        const unsigned int u6 = __float_as_uint(qb.z), u7 = __float_as_uint(qb.w);
        const short8 ahi = mk8((u0 >> 16) | (u1 & 0xFFFF0000u),
                               (u2 >> 16) | (u3 & 0xFFFF0000u),
                               (u4 >> 16) | (u5 & 0xFFFF0000u),
                               (u6 >> 16) | (u7 & 0xFFFF0000u));
        const float l0 = qa.x - __uint_as_float(u0 & 0xFFFF0000u);
        const float l1 = qa.y - __uint_as_float(u1 & 0xFFFF0000u);
        const float l2 = qa.z - __uint_as_float(u2 & 0xFFFF0000u);
        const float l3 = qa.w - __uint_as_float(u3 & 0xFFFF0000u);
        const float l4 = qb.x - __uint_as_float(u4 & 0xFFFF0000u);
        const float l5 = qb.y - __uint_as_float(u5 & 0xFFFF0000u);
        const float l6 = qb.z - __uint_as_float(u6 & 0xFFFF0000u);
        const float l7 = qb.w - __uint_as_float(u7 & 0xFFFF0000u);
        const short8 alo = mk8(
            (__float_as_uint(l0) >> 16) | (__float_as_uint(l1) & 0xFFFF0000u),
            (__float_as_uint(l2) >> 16) | (__float_as_uint(l3) & 0xFFFF0000u),
            (__float_as_uint(l4) >> 16) | (__float_as_uint(l5) & 0xFFFF0000u),
            (__float_as_uint(l6) >> 16) | (__float_as_uint(l7) & 0xFFFF0000u));

        // ---- B fragments (wave-shared LDS, XOR-swizzled) + 12 MFMAs ----
        #pragma unroll
        for (int ng = 0; ng < 4; ++ng) {
            const int e  = ng * 16 + fr;
            const int so = e * KPER + (((st * 4 + fg) ^ xkey) << 3);
            const short8 bh = *(const short8*)&sH[so];
            const short8 bl = *(const short8*)&sL[so];
            acc[ng] = __builtin_amdgcn_mfma_f32_16x16x32_bf16(ahi, bh, acc[ng], 0, 0, 0);
            acc[ng] = __builtin_amdgcn_mfma_f32_16x16x32_bf16(ahi, bl, acc[ng], 0, 0, 0);
            acc[ng] = __builtin_amdgcn_mfma_f32_16x16x32_bf16(alo, bh, acc[ng], 0, 0, 0);
        }

        // ---- refill the just-read buffer with stage st+2 (wave-private) ----
        if (st + 2 < NSTG) {
            // ensure this stage's ds_reads completed before DMA may overwrite
            asm volatile("s_waitcnt lgkmcnt(0)" ::: "memory");
            __builtin_amdgcn_sched_barrier(0);
            float* nb = (st & 1) ? xb1 : xb0;
            ISSUE_X(nb, st + 2)
        }
    }
#undef ISSUE_X

    // ---- store partials [n][s][e] ----
    // C/D layout: col = fr (expert), row = fg*4 + r (token)
    #pragma unroll
    for (int r = 0; r < 4; ++r) {
        const int n = wtok + fg * 4 + r;
        float* __restrict__ pp = part + ((size_t)n * SPLITK + s) * NEXP;
        #pragma unroll
        for (int ng = 0; ng < 4; ++ng)
            pp[ng * 16 + fr] = acc[ng][r];
    }
}

// ---------------- Kernel 3: softmax + group-limited top-k routing ------------
__global__ __launch_bounds__(256) void route_kernel(
    const float* __restrict__ part, float* __restrict__ outW,
    float* __restrict__ outI, float* __restrict__ counts)
{
    __shared__ int hist[NEXP];
    const int tid = threadIdx.x;
    if (tid < NEXP) hist[tid] = 0;
    __syncthreads();

    const int lane = tid & 63;
    const int wv   = tid >> 6;   // wave 0..3
    const int tok_base = blockIdx.x * 32 + wv * 8;

    for (int t = 0; t < 8; ++t) {
        const int n = tok_base + t;
        // sum split-K partials (layout [n][s][e]): 4 KB contiguous per token
        float L = 0.0f;
        #pragma unroll
        for (int s = 0; s < SPLITK; ++s)
            L += part[((size_t)n * SPLITK + s) * NEXP + lane];

        // softmax over 64 experts (wave = expert axis)
        float m = L;
        #pragma unroll
        for (int off = 32; off > 0; off >>= 1) m = fmaxf(m, __shfl_xor(m, off));
        float p = expf(L - m);
        float ssum = p;
        #pragma unroll
        for (int off = 32; off > 0; off >>= 1) ssum += __shfl_xor(ssum, off);
        const float score = p / ssum;

        // group max within each 8-lane group
        float gm = score;
        gm = fmaxf(gm, __shfl_xor(gm, 1));
        gm = fmaxf(gm, __shfl_xor(gm, 2));
        gm = fmaxf(gm, __shfl_xor(gm, 4));

        // top-4 groups (ties -> lower index)
        float ga[8];
        #pragma unroll
        for (int g = 0; g < 8; ++g) ga[g] = __shfl(gm, g * 8);
        unsigned selmask = 0u;
        #pragma unroll
        for (int r = 0; r < 4; ++r) {
            float best = -INFINITY; int bg = 0;
            #pragma unroll
            for (int g = 0; g < 8; ++g) {
                bool taken  = (selmask >> g) & 1u;
                bool better = (!taken) && (ga[g] > best);
                bg   = better ? g : bg;
                best = better ? ga[g] : best;
            }
            selmask |= (1u << bg);
        }

        // mask non-selected groups, wave-wide top-4 (ties -> lower idx)
        float ms = ((selmask >> (lane >> 3)) & 1u) ? score : -INFINITY;
        float wk[4]; int wi[4];
        #pragma unroll
        for (int r = 0; r < 4; ++r) {
            float v = ms; int ix = lane;
            #pragma unroll
            for (int off = 32; off > 0; off >>= 1) {
                float vo = __shfl_xor(v, off);
                int   io = __shfl_xor(ix, off);
                if (vo > v || (vo == v && io < ix)) { v = vo; ix = io; }
            }
            wk[r] = v; wi[r] = ix;
            if (lane == ix) ms = -INFINITY;
        }

        if (lane == 0) {
            *(float4*)&outW[(size_t)n * 4] = make_float4(wk[0], wk[1], wk[2], wk[3]);
            *(float4*)&outI[(size_t)n * 4] =
                make_float4((float)wi[0], (float)wi[1], (float)wi[2], (float)wi[3]);
            atomicAdd(&hist[wi[0]], 1);
            atomicAdd(&hist[wi[1]], 1);
            atomicAdd(&hist[wi[2]], 1);
            atomicAdd(&hist[wi[3]], 1);
        }
    }

    __syncthreads();
    if (tid < NEXP) atomicAdd(&counts[tid], (float)hist[tid]);
}

extern "C" void kernel_launch(void* const* d_in, const int* in_sizes, int n_in,
                              void* d_out, int out_size, void* d_ws, size_t ws_size,
                              hipStream_t stream) {
    const float* X = (const float*)d_in[0];
    const float* W = (const float*)d_in[1];

    float* outW   = (float*)d_out;                    // [N,4] weights
    float* outI   = outW + (size_t)NTOK * KTOP;       // [N,4] indices (as float)
    float* counts = outW + (size_t)2 * NTOK * KTOP;   // [64]  counts  (as float)

    float*          part = (float*)d_ws;                              // 64 MB
    unsigned short* Whi  = (unsigned short*)(part + (size_t)NTOK * SPLITK * NEXP);
    unsigned short* Wlo  = Whi + (size_t)NEXP * DDIM;

    prep_kernel<<<(NEXP * DDIM) / 256, 256, 0, stream>>>(W, Whi, Wlo, counts);
    gemm_kernel<<<NBLK, 256, 0, stream>>>(X, Whi, Wlo, part);
    route_kernel<<<NTOK / 32, 256, 0, stream>>>(part, outW, outI, counts);
}

// Round 13
// 108.201 us; speedup vs baseline: 1.4268x; 1.0639x over previous
//
#include <hip/hip_runtime.h>
#include <math.h>

// Problem constants
#define NTOK 16384
#define DDIM 4096
#define NEXP 64
#define KTOP 4

// GEMM config
#define SPLITK 4
#define KPER (DDIM / SPLITK)   // 1024 k per split
#define BK 32                  // k per stage (one 16x16x32 MFMA k-step)
#define NSTG (KPER / BK)       // 32 stages
#define TPB 128                // tokens per block = 8 waves x 16 rows
#define NBLK ((NTOK / TPB) * SPLITK)  // 512 blocks -> 2/CU

typedef __attribute__((ext_vector_type(8))) short short8;
typedef __attribute__((ext_vector_type(4))) float f32x4;

// ws layout: part [NTOK][SPLITK][NEXP] f32 = 16 MB ; Whi 512 KB ; Wlo 512 KB

__device__ __forceinline__ unsigned short f2bf_rtn(float x) {
    unsigned int b = __float_as_uint(x);
    return (unsigned short)((b + 0x7FFFu + ((b >> 16) & 1u)) >> 16);
}
__device__ __forceinline__ float bf2f(unsigned short h) {
    return __uint_as_float(((unsigned int)h) << 16);
}
__device__ __forceinline__ short8 mk8(unsigned int a, unsigned int b,
                                      unsigned int c, unsigned int d) {
    union { unsigned int u[4]; short8 s; } p;
    p.u[0] = a; p.u[1] = b; p.u[2] = c; p.u[3] = d;
    return p.s;
}
__device__ __forceinline__ void gl2lds16(const void* g, void* l) {
    __builtin_amdgcn_global_load_lds(
        (const __attribute__((address_space(1))) unsigned int*)g,
        (__attribute__((address_space(3))) unsigned int*)l, 16, 0, 0);
}

// ---------------- Kernel 1: split W into bf16 hi/lo, zero counts -------------
__global__ __launch_bounds__(256) void prep_kernel(
    const float* __restrict__ W, unsigned short* __restrict__ Whi,
    unsigned short* __restrict__ Wlo, float* __restrict__ counts)
{
    int idx = blockIdx.x * 256 + threadIdx.x;   // 0 .. 64*4096
    float x = W[idx];
    unsigned short h = f2bf_rtn(x);
    float lo = x - bf2f(h);
    Whi[idx] = h;
    Wlo[idx] = f2bf_rtn(lo);
    if (blockIdx.x == 0 && threadIdx.x < NEXP) counts[threadIdx.x] = 0.0f;
}

// ---------------- Kernel 2: bf16x3 MFMA GEMM, 3-deep no-drain pipeline -------
// 512 blocks x 512 threads (8 waves), LDS 72 KB -> 2 blocks/CU.
// TRIPLE-buffered X and W LDS slots; stage st+2 issued at TOP of stage st;
// end-of-stage sync = `s_waitcnt vmcnt(3)` (st+1's batch done, st+2's stays
// in flight -- NEVER drains) + sched_barrier + RAW s_barrier (no compiler
// vmcnt(0) drain). Coverage ~2 stage-walls > queue-inflated HBM latency.
__global__ __launch_bounds__(512, 4) void gemm_kernel(
    const float* __restrict__ X, const unsigned short* __restrict__ Whi,
    const unsigned short* __restrict__ Wlo, float* __restrict__ part)
{
    __shared__ float          sX[3][TPB * BK];    // 3 x 16 KB
    __shared__ unsigned short sH[3][NEXP * BK];   // 3 x 4 KB
    __shared__ unsigned short sL[3][NEXP * BK];   // 3 x 4 KB

    const int tid  = threadIdx.x;
    const int lane = tid & 63;
    const int w    = tid >> 6;                 // wave 0..7
    const int tb   = blockIdx.x >> 2;          // token block 0..127
    const int s    = blockIdx.x & 3;           // k-split    0..3
    const int kbase = s * KPER;
    const int tok0 = tb * TPB;

    // ---- X staging: wave w issues 2 instr/stage; instr j covers rows
    // [ (w*2+j)*8, +8 ): lane l -> row r = seg*8+(l>>3), LDS piece l&7,
    // source piece = (l&7) ^ (r&7)  (XOR involution, source-side; LDS linear).
    const int r0 = (w * 2    ) * 8 + (lane >> 3);
    const int r1 = (w * 2 + 1) * 8 + (lane >> 3);
    const int xp = lane & 7;
    const float* xsrc0 = X + (size_t)(tok0 + r0) * DDIM + kbase + ((xp ^ (r0 & 7)) << 2);
    const float* xsrc1 = X + (size_t)(tok0 + r1) * DDIM + kbase + ((xp ^ (r1 & 7)) << 2);
    const int xdst0 = (w * 2    ) * 256;       // float offset within slot
    const int xdst1 = (w * 2 + 1) * 256;

    // ---- W staging: 1 instr/wave/stage; waves 0-3 stage hi, 4-7 stage lo.
    // Piece-major LDS layout [ng][fg][e]: dest short off = (w&3)*512 + lane*8;
    // lane l -> piece p = l>>4 (k-subgroup), expert e = (w&3)*16 + (l&15).
    const unsigned short* const wtab_src = (w < 4) ? Whi : Wlo;
    const int eb = w & 3;
    const int we = eb * 16 + (lane & 15);
    const unsigned short* wsrc = wtab_src + (size_t)we * DDIM + kbase + (lane >> 4) * 8;
    const int wdst = eb * 512 + lane * 8;      // short offset within slot
    unsigned short (* const wtab_dst)[NEXP * BK] = (w < 4) ? sH : sL;

#define ISSUE(st_, slot_)                                                   \
    {                                                                       \
        gl2lds16(xsrc0 + (st_) * BK, &sX[slot_][xdst0]);                    \
        gl2lds16(xsrc1 + (st_) * BK, &sX[slot_][xdst1]);                    \
        gl2lds16(wsrc  + (st_) * BK, &wtab_dst[slot_][wdst]);               \
    }

    // ---- prologue: stages 0,1 in flight; single full drain publishes both --
    ISSUE(0, 0)
    ISSUE(1, 1)
    __syncthreads();

    // ---- fragment geometry ----
    const int fr = lane & 15;                  // token row / expert col in frag
    const int fg = lane >> 4;                  // k subgroup 0..3
    const int aoff = (w * 16 + fr) * BK;       // A row base (floats)
    const int akey = fr & 7;

    f32x4 acc[4];
    #pragma unroll
    for (int ng = 0; ng < 4; ++ng) acc[ng] = (f32x4){0.f, 0.f, 0.f, 0.f};

    #pragma unroll
    for (int st = 0; st < NSTG; ++st) {
        const int slot = st % 3;               // compile-time under full unroll

        // ---- issue stage st+2 into slot (st+2)%3 (freed after stage st-1) --
        if (st + 2 < NSTG) ISSUE(st + 2, (st + 2) % 3)

        // ---- A fragment from LDS (row-XOR swizzled) ----
        const float4 qa = *(const float4*)&sX[slot][aoff + (((fg * 2    ) ^ akey) << 2)];
        const float4 qb = *(const float4*)&sX[slot][aoff + (((fg * 2 + 1) ^ akey) << 2)];

        // ---- RTZ split fp32 -> bf16 hi/lo ----
        const unsigned int u0 = __float_as_uint(qa.x), u1 = __float_as_uint(qa.y);
        const unsigned int u2 = __float_as_uint(qa.z), u3 = __float_as_uint(qa.w);
        const unsigned int u4 = __float_as_uint(qb.x), u5 = __float_as_uint(qb.y);
        const unsigned int u6 = __float_as_uint(qb.z), u7 = __float_as_uint(qb.w);
        const short8 ahi = mk8((u0 >> 16) | (u1 & 0xFFFF0000u),
                               (u2 >> 16) | (u3 & 0xFFFF0000u),
                               (u4 >> 16) | (u5 & 0xFFFF0000u),
                               (u6 >> 16) | (u7 & 0xFFFF0000u));
        const float l0 = qa.x - __uint_as_float(u0 & 0xFFFF0000u);
        const float l1 = qa.y - __uint_as_float(u1 & 0xFFFF0000u);
        const float l2 = qa.z - __uint_as_float(u2 & 0xFFFF0000u);
        const float l3 = qa.w - __uint_as_float(u3 & 0xFFFF0000u);
        const float l4 = qb.x - __uint_as_float(u4 & 0xFFFF0000u);
        const float l5 = qb.y - __uint_as_float(u5 & 0xFFFF0000u);
        const float l6 = qb.z - __uint_as_float(u6 & 0xFFFF0000u);
        const float l7 = qb.w - __uint_as_float(u7 & 0xFFFF0000u);
        const short8 alo = mk8(
            (__float_as_uint(l0) >> 16) | (__float_as_uint(l1) & 0xFFFF0000u),
            (__float_as_uint(l2) >> 16) | (__float_as_uint(l3) & 0xFFFF0000u),
            (__float_as_uint(l4) >> 16) | (__float_as_uint(l5) & 0xFFFF0000u),
            (__float_as_uint(l6) >> 16) | (__float_as_uint(l7) & 0xFFFF0000u));

        // ---- B fragments (piece-major layout) + 12 MFMAs ----
        #pragma unroll
        for (int ng = 0; ng < 4; ++ng) {
            const int bo = ng * 512 + fg * 128 + fr * 8;
            const short8 bh = *(const short8*)&sH[slot][bo];
            const short8 bl = *(const short8*)&sL[slot][bo];
            acc[ng] = __builtin_amdgcn_mfma_f32_16x16x32_bf16(ahi, bh, acc[ng], 0, 0, 0);
            acc[ng] = __builtin_amdgcn_mfma_f32_16x16x32_bf16(ahi, bl, acc[ng], 0, 0, 0);
            acc[ng] = __builtin_amdgcn_mfma_f32_16x16x32_bf16(alo, bh, acc[ng], 0, 0, 0);
        }

        // ---- end-of-stage sync: st+1's batch done; st+2's stays in flight --
        if (st < NSTG - 1) {
            if (st < NSTG - 2) {
                asm volatile("s_waitcnt vmcnt(3)" ::: "memory");
            } else {
                asm volatile("s_waitcnt vmcnt(0)" ::: "memory");
            }
            __builtin_amdgcn_sched_barrier(0);
            __builtin_amdgcn_s_barrier();      // raw barrier: NO vmcnt(0) drain
        }
    }
#undef ISSUE

    // ---- store partials [n][s][e] ----
    // C/D layout: col = fr (expert), row = fg*4 + r (token)
    #pragma unroll
    for (int r = 0; r < 4; ++r) {
        const int n = tok0 + w * 16 + fg * 4 + r;
        float* __restrict__ pp = part + ((size_t)n * SPLITK + s) * NEXP;
        #pragma unroll
        for (int ng = 0; ng < 4; ++ng)
            pp[ng * 16 + fr] = acc[ng][r];
    }
}

// ---------------- Kernel 3: softmax + group-limited top-k routing ------------
__global__ __launch_bounds__(256) void route_kernel(
    const float* __restrict__ part, float* __restrict__ outW,
    float* __restrict__ outI, float* __restrict__ counts)
{
    __shared__ int hist[NEXP];
    const int tid = threadIdx.x;
    if (tid < NEXP) hist[tid] = 0;
    __syncthreads();

    const int lane = tid & 63;
    const int wv   = tid >> 6;   // wave 0..3
    const int tok_base = blockIdx.x * 32 + wv * 8;

    for (int t = 0; t < 8; ++t) {
        const int n = tok_base + t;
        // sum split-K partials (layout [n][s][e]): 1 KB contiguous per token
        float L = 0.0f;
        #pragma unroll
        for (int s = 0; s < SPLITK; ++s)
            L += part[((size_t)n * SPLITK + s) * NEXP + lane];

        // softmax over 64 experts (wave = expert axis)
        float m = L;
        #pragma unroll
        for (int off = 32; off > 0; off >>= 1) m = fmaxf(m, __shfl_xor(m, off));
        float p = expf(L - m);
        float ssum = p;
        #pragma unroll
        for (int off = 32; off > 0; off >>= 1) ssum += __shfl_xor(ssum, off);
        const float score = p / ssum;

        // group max within each 8-lane group
        float gm = score;
        gm = fmaxf(gm, __shfl_xor(gm, 1));
        gm = fmaxf(gm, __shfl_xor(gm, 2));
        gm = fmaxf(gm, __shfl_xor(gm, 4));

        // top-4 groups (ties -> lower index)
        float ga[8];
        #pragma unroll
        for (int g = 0; g < 8; ++g) ga[g] = __shfl(gm, g * 8);
        unsigned selmask = 0u;
        #pragma unroll
        for (int r = 0; r < 4; ++r) {
            float best = -INFINITY; int bg = 0;
            #pragma unroll
            for (int g = 0; g < 8; ++g) {
                bool taken  = (selmask >> g) & 1u;
                bool better = (!taken) && (ga[g] > best);
                bg   = better ? g : bg;
                best = better ? ga[g] : best;
            }
            selmask |= (1u << bg);
        }

        // mask non-selected groups, wave-wide top-4 (ties -> lower idx)
        float ms = ((selmask >> (lane >> 3)) & 1u) ? score : -INFINITY;
        float wk[4]; int wi[4];
        #pragma unroll
        for (int r = 0; r < 4; ++r) {
            float v = ms; int ix = lane;
            #pragma unroll
            for (int off = 32; off > 0; off >>= 1) {
                float vo = __shfl_xor(v, off);
                int   io = __shfl_xor(ix, off);
                if (vo > v || (vo == v && io < ix)) { v = vo; ix = io; }
            }
            wk[r] = v; wi[r] = ix;
            if (lane == ix) ms = -INFINITY;
        }

        if (lane == 0) {
            *(float4*)&outW[(size_t)n * 4] = make_float4(wk[0], wk[1], wk[2], wk[3]);
            *(float4*)&outI[(size_t)n * 4] =
                make_float4((float)wi[0], (float)wi[1], (float)wi[2], (float)wi[3]);
            atomicAdd(&hist[wi[0]], 1);
            atomicAdd(&hist[wi[1]], 1);
            atomicAdd(&hist[wi[2]], 1);
            atomicAdd(&hist[wi[3]], 1);
        }
    }

    __syncthreads();
    if (tid < NEXP) atomicAdd(&counts[tid], (float)hist[tid]);
}

extern "C" void kernel_launch(void* const* d_in, const int* in_sizes, int n_in,
                              void* d_out, int out_size, void* d_ws, size_t ws_size,
                              hipStream_t stream) {
    const float* X = (const float*)d_in[0];
    const float* W = (const float*)d_in[1];

    float* outW   = (float*)d_out;                    // [N,4] weights
    float* outI   = outW + (size_t)NTOK * KTOP;       // [N,4] indices (as float)
    float* counts = outW + (size_t)2 * NTOK * KTOP;   // [64]  counts  (as float)

    float*          part = (float*)d_ws;                              // 16 MB
    unsigned short* Whi  = (unsigned short*)(part + (size_t)NTOK * SPLITK * NEXP);
    unsigned short* Wlo  = Whi + (size_t)NEXP * DDIM;

    prep_kernel<<<(NEXP * DDIM) / 256, 256, 0, stream>>>(W, Whi, Wlo, counts);
    gemm_kernel<<<NBLK, 512, 0, stream>>>(X, Whi, Wlo, part);
    route_kernel<<<NTOK / 32, 256, 0, stream>>>(part, outW, outI, counts);
}